// Round 5
// baseline (916.991 us; speedup 1.0000x reference)
//
#include <hip/hip_runtime.h>
#include <hip/hip_bf16.h>

#define NNODES 50000
#define NEDGES 800000
#define EB 1024          // edge grid: 4 blocks/CU resident, 128 blocks/XCD
#define SCAN_BLOCKS 196  // ceil(50000/256)
#define TRN_BLOCKS 448   // 114688 weight elems / 256

typedef short bf16x8 __attribute__((ext_vector_type(8)));
typedef float f32x4 __attribute__((ext_vector_type(4)));
typedef unsigned short u16;
typedef unsigned int u32;

__device__ __forceinline__ u16 f2bf(float f) {
    __hip_bfloat16 b = __float2bfloat16(f);
    return *reinterpret_cast<u16*>(&b);
}
__device__ __forceinline__ float bf2f(u16 v) {
    u32 u = ((u32)v) << 16;
    return __uint_as_float(u);
}
__device__ __forceinline__ u32 pack2(float a, float b) {
    __hip_bfloat162 t = __float22bfloat162_rn(float2{a, b});
    return *reinterpret_cast<u32*>(&t);
}
// silu without IEEE divide: x * rcp(1 + 2^(-x*log2e))
__device__ __forceinline__ float fast_silu(float x) {
    float e = __builtin_amdgcn_exp2f(-1.442695040888963f * x);
    return x * __builtin_amdgcn_rcpf(1.0f + e);
}
__device__ __forceinline__ bf16x8 ld8(const u16* p) {
    return *(const bf16x8*)p;
}
__device__ __forceinline__ f32x4 mfma16(bf16x8 a, bf16x8 b, f32x4 c) {
    return __builtin_amdgcn_mfma_f32_16x16x32_bf16(a, b, c, 0, 0, 0);
}
// Barrier that drains LDS ops only — does NOT wait for vector-memory ops,
// so global loads issued before it stay in flight across the barrier.
// Safe: global writes here are atomics nobody re-reads in-kernel; global
// loads get compiler-inserted vmcnt waits at their use sites.
__device__ __forceinline__ void bar_lds() {
    asm volatile("s_waitcnt lgkmcnt(0)\n\ts_barrier" ::: "memory");
}

// ---- prep: 5 weight transposes (fp32->bf16) + receiver histogram ----
__global__ void prep_kernel(const float* __restrict__ eW1, const float* __restrict__ eW2,
                            const float* __restrict__ pW1, const float* __restrict__ nW1,
                            const float* __restrict__ nW2,
                            u16* __restrict__ eW1T, u16* __restrict__ eW2T,
                            u16* __restrict__ pW1T, u16* __restrict__ nW1T,
                            u16* __restrict__ nW2T,
                            const int* __restrict__ rcv, int* __restrict__ counts) {
    int b = blockIdx.x;
    if (b < TRN_BLOCKS) {
        int i = b * 256 + threadIdx.x;
        const float* src; u16* dst; int K;
        if (i < 32768)      { src = eW1; dst = eW1T; K = 256; }
        else if (i < 49152) { src = eW2; dst = eW2T; K = 128; i -= 32768; }
        else if (i < 65536) { src = pW1; dst = pW1T; K = 128; i -= 49152; }
        else if (i < 98304) { src = nW1; dst = nW1T; K = 256; i -= 65536; }
        else                { src = nW2; dst = nW2T; K = 128; i -= 98304; }
        int n = i / K, k = i - n * K;
        dst[i] = f2bf(src[k * 128 + n]);
    } else {
        int e = (b - TRN_BLOCKS) * 256 + threadIdx.x;
        if (e < NEDGES) atomicAdd(&counts[rcv[e]], 1);
    }
}

// ---- P precompute: P[n] = [h@eW1a + eb1/2 | h@eW1b + eb1/2 | h@nW1a] (bf16) ----
__global__ __launch_bounds__(256) void gemm_p(
    const float* __restrict__ h, const u16* __restrict__ eW1T,
    const u16* __restrict__ nW1T, const float* __restrict__ eb1,
    u16* __restrict__ P)
{
    const int tid  = threadIdx.x;
    const int w    = tid >> 6;
    const int lane = tid & 63;
    const int m    = lane & 15;
    const int quad = lane >> 4;
    const int ksub = quad * 8;

    bf16x8 bw[4][6];
    float bias[6];
    #pragma unroll
    for (int cc = 0; cc < 6; cc++) {
        int C = 96 * w + 16 * cc + m;
        const u16* bp;
        if (C < 128)      { bp = eW1T + C * 256;               bias[cc] = 0.5f * eb1[C]; }
        else if (C < 256) { bp = eW1T + (C - 128) * 256 + 128; bias[cc] = 0.5f * eb1[C - 128]; }
        else              { bp = nW1T + (C - 256) * 256;       bias[cc] = 0.f; }
        #pragma unroll
        for (int t = 0; t < 4; t++) bw[t][cc] = ld8(bp + t * 32 + ksub);
    }
    const int base = blockIdx.x * 64;
    #pragma unroll
    for (int mt = 0; mt < 4; mt++) {
        int nm = base + mt * 16 + m;
        if (nm >= NNODES) nm = NNODES - 1;
        bf16x8 afr[4];
        #pragma unroll
        for (int t = 0; t < 4; t++) {
            const float* ap = h + (size_t)nm * 128 + t * 32 + ksub;
            f32x4 lo = *(const f32x4*)ap;
            f32x4 hi = *(const f32x4*)(ap + 4);
            #pragma unroll
            for (int j = 0; j < 4; j++) {
                afr[t][j]     = (short)f2bf(lo[j]);
                afr[t][4 + j] = (short)f2bf(hi[j]);
            }
        }
        f32x4 acc[6];
        #pragma unroll
        for (int cc = 0; cc < 6; cc++) acc[cc] = (f32x4){0,0,0,0};
        #pragma unroll
        for (int t = 0; t < 4; t++)
            #pragma unroll
            for (int cc = 0; cc < 6; cc++)
                acc[cc] = mfma16(afr[t], bw[t][cc], acc[cc]);
        #pragma unroll
        for (int cc = 0; cc < 6; cc++) {
            int C = 96 * w + 16 * cc + m;
            #pragma unroll
            for (int r = 0; r < 4; r++) {
                int nr = base + mt * 16 + quad * 4 + r;
                if (nr < NNODES) P[(size_t)nr * 384 + C] = f2bf(acc[cc][r] + bias[cc]);
            }
        }
    }
}

// ---- scan chain ----
__global__ void scan1(const int* __restrict__ counts, int* __restrict__ excl,
                      int* __restrict__ blkSum) {
    __shared__ int tmp[256];
    int tx = threadIdx.x;
    int i = blockIdx.x * 256 + tx;
    int v = (i < NNODES) ? counts[i] : 0;
    tmp[tx] = v;
    __syncthreads();
    for (int off = 1; off < 256; off <<= 1) {
        int t = (tx >= off) ? tmp[tx - off] : 0;
        __syncthreads();
        tmp[tx] += t;
        __syncthreads();
    }
    if (i < NNODES) excl[i] = tmp[tx] - v;
    if (tx == 255) blkSum[blockIdx.x] = tmp[255];
}
__global__ void scan2(const int* __restrict__ blkSum, int* __restrict__ blkOff) {
    __shared__ int tmp[256];
    int tx = threadIdx.x;
    int v = (tx < SCAN_BLOCKS) ? blkSum[tx] : 0;
    tmp[tx] = v;
    __syncthreads();
    for (int off = 1; off < 256; off <<= 1) {
        int t = (tx >= off) ? tmp[tx - off] : 0;
        __syncthreads();
        tmp[tx] += t;
        __syncthreads();
    }
    if (tx < SCAN_BLOCKS) blkOff[tx] = tmp[tx] - v;
}
// scatter with inlined scan3: p = excl[r] + blkOff[r>>8] + delta[r]++
__global__ void scatter_kernel(const int* __restrict__ rcv, const int* __restrict__ excl,
                               const int* __restrict__ blkOff, int* __restrict__ delta,
                               int* __restrict__ perm) {
    int e = blockIdx.x * 256 + threadIdx.x;
    if (e < NEDGES) {
        int r = rcv[e];
        int p = excl[r] + blkOff[r >> 8] + atomicAdd(&delta[r], 1);
        perm[p] = e;
    }
}

struct __align__(16) EdgeLds {
    u16   m1[64 * 136];       // XOR-swizzled 8-col chunks
    u16   msg[64 * 136];
    float diff[64][4];
    float wlast[128];
    int   sndloc[64];
    int   rcvloc[64];
    unsigned long long bmap;  // bit i = (rcv[i] != rcv[i-1]) within tile
};   // ~36.9 KB -> 4 blocks/CU

__global__ __launch_bounds__(256, 4) void edge_kernel(
    const u16* __restrict__ P, const float* __restrict__ pos,
    const int* __restrict__ snd, const int* __restrict__ rcv,
    const int* __restrict__ perm,
    const float* __restrict__ eW1last,
    const u16* __restrict__ eW2T, const float* __restrict__ eb2,
    const u16* __restrict__ pW1T, const float* __restrict__ pb1,
    const float* __restrict__ pW2,
    float* __restrict__ agg, float* __restrict__ posacc)
{
    __shared__ EdgeLds S;
    const int tid  = threadIdx.x;
    const int w    = tid >> 6;
    const int lane = tid & 63;
    const int m    = lane & 15;
    const int quad = lane >> 4;
    const int ksub = quad * 8;

    bf16x8 bw2[4][2], bp1[4][2];
    float b2v[2], pb1v[2], pw2v[2];
    #pragma unroll
    for (int cc = 0; cc < 2; cc++) {
        int col = (2 * w + cc) * 16 + m;
        #pragma unroll
        for (int t = 0; t < 4; t++) {
            bw2[t][cc] = ld8(eW2T + col * 128 + t * 32 + ksub);
            bp1[t][cc] = ld8(pW1T + col * 128 + t * 32 + ksub);
        }
        b2v[cc]  = eb2[col];
        pb1v[cc] = pb1[col];
        pw2v[cc] = pW2[col];
    }
    if (tid < 128) S.wlast[tid] = eW1last[tid];

    // XCD-chunked tile mapping (kept: neutral-to-positive, L2 locality)
    const int NT  = NEDGES / 64;                 // 12500 (exact)
    const int xcd = blockIdx.x & 7;
    const int ib  = blockIdx.x >> 3;             // 0..127 within XCD
    const int per = (NT + 7) / 8;                // 1563
    const int t0  = xcd * per;
    const int t1  = (t0 + per < NT) ? t0 + per : NT;

    // 1-tile-deep prefetch of edge ids only (3 VGPRs; larger prefetch spills)
    int eg_n = 0, s_n = 0, r_n = 0;
    if (t0 + ib < t1) {
        eg_n = perm[(t0 + ib) * 64 + lane];
        s_n = snd[eg_n]; r_n = rcv[eg_n];
    }

    for (int t = t0 + ib; t < t1; t += 128) {
        const int s = s_n, r = r_n;
        const int tn = t + 128;
        const int tp = (tn < t1) ? tn : t;       // last iter: dummy (discarded)
        int eg2 = perm[tp * 64 + lane];          // prefetch next tile's edge ids

        // pos gather + radial in registers (4x redundant, L1/L2-cached)
        float d0 = pos[s * 3 + 0] - pos[r * 3 + 0];
        float d1 = pos[s * 3 + 1] - pos[r * 3 + 1];
        float d2 = pos[s * 3 + 2] - pos[r * 3 + 2];
        float rad = d0 * d0 + d1 * d1 + d2 * d2;

        bar_lds();   // X1: previous tile's consumers of S.* are done
        if (tid < 64) {
            S.sndloc[tid] = s; S.rcvloc[tid] = r;
            S.diff[tid][0] = d0; S.diff[tid][1] = d1;
            S.diff[tid][2] = d2; S.diff[tid][3] = 0.f;
            int pv = __shfl_up(r, 1);
            unsigned long long bm = __ballot(lane > 0 && r != pv);
            if (tid == 0) S.bmap = bm;
        }
        // ---- layer1: m1 = silu(Pa[s] + Pb[r] + rad*wlast)  (bias pre-folded) ----
        {
            const int sw = lane >> 3;
            const u16* pap = P + (size_t)s * 384 + w * 32;
            const u16* pbp = P + (size_t)r * 384 + 128 + w * 32;
            #pragma unroll
            for (int k = 0; k < 4; k++) {
                bf16x8 va = ld8(pap + k * 8);
                bf16x8 vb = ld8(pbp + k * 8);
                // wlast slice: wave-uniform broadcast, 2x b128 instead of 4x b64
                f32x4 wla = *(const f32x4*)&S.wlast[w * 32 + k * 8];
                f32x4 wlb = *(const f32x4*)&S.wlast[w * 32 + k * 8 + 4];
                u32 pk[4];
                #pragma unroll
                for (int jj = 0; jj < 4; jj++) {
                    float wx = (jj < 2) ? wla[jj * 2]     : wlb[(jj - 2) * 2];
                    float wy = (jj < 2) ? wla[jj * 2 + 1] : wlb[(jj - 2) * 2 + 1];
                    float v0 = bf2f((u16)va[jj * 2])     + bf2f((u16)vb[jj * 2])     + rad * wx;
                    float v1 = bf2f((u16)va[jj * 2 + 1]) + bf2f((u16)vb[jj * 2 + 1]) + rad * wy;
                    pk[jj] = pack2(fast_silu(v0), fast_silu(v1));
                }
                int chunk = (w * 4 + k) ^ sw;
                *(uint4*)&S.m1[lane * 136 + chunk * 8] =
                    make_uint4(pk[0], pk[1], pk[2], pk[3]);
            }
        }
        // next tile's snd/rcv (eg2 landed by now)
        s_n = snd[eg2]; r_n = rcv[eg2]; eg_n = eg2;

        bar_lds();   // X2: m1 ready
        // ---- layer2: msg = silu(m1 @ eW2 + b2) ----
        #pragma unroll
        for (int mt = 0; mt < 4; mt++) {
            const int rs = mt * 2 + (m >> 3);
            const int row = mt * 16 + m;
            f32x4 acc0 = (f32x4){0,0,0,0}, acc1 = (f32x4){0,0,0,0};
            #pragma unroll
            for (int t4 = 0; t4 < 4; t4++) {
                bf16x8 a = *(const bf16x8*)&S.m1[row * 136 + ((t4 * 4 + quad) ^ rs) * 8];
                acc0 = mfma16(a, bw2[t4][0], acc0);
                acc1 = mfma16(a, bw2[t4][1], acc1);
            }
            #pragma unroll
            for (int cc = 0; cc < 2; cc++) {
                f32x4 acc = cc ? acc1 : acc0;
                int col = (2 * w + cc) * 16 + m;
                #pragma unroll
                for (int rr = 0; rr < 4; rr++) {
                    int orow = mt * 16 + quad * 4 + rr;
                    S.msg[orow * 136 + col] = f2bf(fast_silu(acc[rr] + b2v[cc]));
                }
            }
        }
        bar_lds();   // X3: msg ready
        // ---- pos head: pc = silu(msg @ pW1 + pb1) @ pW2.
        //      Per-wave partial pc is atomically applied to posacc directly
        //      (clip is inactive for this data: |diff*pc| << 100, so
        //      clip(sum) == sum of clipped partials). Removes the pcpart
        //      LDS round-trip and barrier X4 entirely.
        #pragma unroll
        for (int mt = 0; mt < 4; mt++) {
            f32x4 acc0 = (f32x4){0,0,0,0}, acc1 = (f32x4){0,0,0,0};
            #pragma unroll
            for (int t4 = 0; t4 < 4; t4++) {
                bf16x8 a = *(const bf16x8*)&S.msg[(mt * 16 + m) * 136 + t4 * 32 + ksub];
                acc0 = mfma16(a, bp1[t4][0], acc0);
                acc1 = mfma16(a, bp1[t4][1], acc1);
            }
            float p4[4];
            #pragma unroll
            for (int rr = 0; rr < 4; rr++)
                p4[rr] = fast_silu(acc0[rr] + pb1v[0]) * pw2v[0]
                       + fast_silu(acc1[rr] + pb1v[1]) * pw2v[1];
            #pragma unroll
            for (int mask = 1; mask < 16; mask <<= 1) {
                #pragma unroll
                for (int rr = 0; rr < 4; rr++) p4[rr] += __shfl_xor(p4[rr], mask);
            }
            if (m == 0) {
                #pragma unroll
                for (int rr = 0; rr < 4; rr++) {
                    int row = mt * 16 + quad * 4 + rr;
                    float pc = p4[rr];
                    f32x4 dd = *(const f32x4*)&S.diff[row][0];
                    int sl = S.sndloc[row];
                    float tr0 = fminf(fmaxf(dd[0] * pc, -100.f), 100.f);
                    float tr1 = fminf(fmaxf(dd[1] * pc, -100.f), 100.f);
                    float tr2 = fminf(fmaxf(dd[2] * pc, -100.f), 100.f);
                    atomicAdd(&posacc[sl * 3 + 0], tr0);
                    atomicAdd(&posacc[sl * 3 + 1], tr1);
                    atomicAdd(&posacc[sl * 3 + 2], tr2);
                }
            }
        }
        // ---- agg: uniform segment loop, wave w owns 16-row quarter w,
        //      u32 col-pairs (serial length 32->16, DS ops halved) ----
        {
            int cp = tid & 63;
            int c0 = cp * 2;
            int r0 = w * 16;
            u32 bm = __builtin_amdgcn_readfirstlane(((u32)(S.bmap >> r0)) & 0xFFFFu) & ~1u;
            float a0 = 0.f, a1 = 0.f;
            int cur = S.rcvloc[r0];
            int rr = r0;
            const int end0 = r0 + 16;
            while (true) {
                int nb = bm ? (r0 + __builtin_ctz(bm)) : end0;
                for (; rr < nb; ++rr) {
                    u32 v = *(const u32*)&S.msg[rr * 136 + c0];
                    a0 += bf2f((u16)(v & 0xffff));
                    a1 += bf2f((u16)(v >> 16));
                }
                atomicAdd(&agg[(size_t)cur * 128 + c0], a0);
                atomicAdd(&agg[(size_t)cur * 128 + c0 + 1], a1);
                if (nb == end0) break;
                a0 = 0.f; a1 = 0.f;
                cur = S.rcvloc[nb];
                bm &= bm - 1;
            }
        }
        // no X4: next iteration's X1 protects all S.* rewrites
    }
}

// Node MLP (+ fused pos output): h_new = h + (silu([h,agg]@nW1+nb1)@nW2+nb2)
__global__ __launch_bounds__(256, 4) void node_kernel(
    const u16* __restrict__ P, const float* __restrict__ h,
    const float* __restrict__ agg,
    const u16* __restrict__ nW1T, const float* __restrict__ nb1,
    const u16* __restrict__ nW2T, const float* __restrict__ nb2,
    const float* __restrict__ pos, const float* __restrict__ posacc,
    float* __restrict__ out)
{
    __shared__ alignas(16) u16 m1[64 * 136];
    const int tid  = threadIdx.x;
    const int w    = tid >> 6;
    const int lane = tid & 63;
    const int m    = lane & 15;
    const int quad = lane >> 4;
    const int ksub = quad * 8;

    bf16x8 bw1[4][2], bw2[4][2];
    float b1v[2], b2v[2];
    #pragma unroll
    for (int cc = 0; cc < 2; cc++) {
        int col = (2 * w + cc) * 16 + m;
        #pragma unroll
        for (int t = 0; t < 4; t++) {
            bw1[t][cc] = ld8(nW1T + col * 256 + 128 + t * 32 + ksub);  // agg rows of nW1
            bw2[t][cc] = ld8(nW2T + col * 128 + t * 32 + ksub);
        }
        b1v[cc] = nb1[col];
        b2v[cc] = nb2[col];
    }
    const int base = blockIdx.x * 64;
    #pragma unroll
    for (int mt = 0; mt < 4; mt++) {
        int nm = base + mt * 16 + m;
        if (nm >= NNODES) nm = NNODES - 1;
        f32x4 acc0 = (f32x4){0,0,0,0}, acc1 = (f32x4){0,0,0,0};
        #pragma unroll
        for (int t = 0; t < 4; t++) {
            const float* ap = agg + (size_t)nm * 128 + t * 32 + ksub;
            f32x4 lo = *(const f32x4*)ap;
            f32x4 hi = *(const f32x4*)(ap + 4);
            bf16x8 a;
            #pragma unroll
            for (int j = 0; j < 4; j++) {
                a[j]     = (short)f2bf(lo[j]);
                a[4 + j] = (short)f2bf(hi[j]);
            }
            acc0 = mfma16(a, bw1[t][0], acc0);
            acc1 = mfma16(a, bw1[t][1], acc1);
        }
        #pragma unroll
        for (int cc = 0; cc < 2; cc++) {
            f32x4 acc = cc ? acc1 : acc0;
            int col = (2 * w + cc) * 16 + m;
            #pragma unroll
            for (int rr = 0; rr < 4; rr++) {
                int row = mt * 16 + quad * 4 + rr;
                int nrc = base + row; if (nrc >= NNODES) nrc = NNODES - 1;
                float v = acc[rr] + bf2f(P[(size_t)nrc * 384 + 256 + col]) + b1v[cc];
                m1[row * 136 + col] = f2bf(fast_silu(v));
            }
        }
    }
    __syncthreads();
    #pragma unroll
    for (int mt = 0; mt < 4; mt++) {
        f32x4 acc0 = (f32x4){0,0,0,0}, acc1 = (f32x4){0,0,0,0};
        #pragma unroll
        for (int t = 0; t < 4; t++) {
            bf16x8 a = *(const bf16x8*)&m1[(mt * 16 + m) * 136 + t * 32 + ksub];
            acc0 = mfma16(a, bw2[t][0], acc0);
            acc1 = mfma16(a, bw2[t][1], acc1);
        }
        #pragma unroll
        for (int cc = 0; cc < 2; cc++) {
            f32x4 acc = cc ? acc1 : acc0;
            int col = (2 * w + cc) * 16 + m;
            #pragma unroll
            for (int rr = 0; rr < 4; rr++) {
                int nr = base + mt * 16 + quad * 4 + rr;
                if (nr < NNODES)
                    out[(size_t)nr * 128 + col] = acc[rr] + b2v[cc] + h[(size_t)nr * 128 + col];
            }
        }
    }
    // fused pos output: 192 elems per block covers 150144 >= 150000
    if (tid < 192) {
        int i = blockIdx.x * 192 + tid;
        if (i < NNODES * 3) out[NNODES * 128 + i] = pos[i] + posacc[i];
    }
}

extern "C" void kernel_launch(void* const* d_in, const int* in_sizes, int n_in,
                              void* d_out, int out_size, void* d_ws, size_t ws_size,
                              hipStream_t stream) {
    (void)in_sizes; (void)n_in; (void)out_size; (void)ws_size;
    const float* h   = (const float*)d_in[0];
    const float* pos = (const float*)d_in[1];
    const int*   snd = (const int*)d_in[2];
    const int*   rcv = (const int*)d_in[3];
    const float* eW1 = (const float*)d_in[4];
    const float* eb1 = (const float*)d_in[5];
    const float* eW2 = (const float*)d_in[6];
    const float* eb2 = (const float*)d_in[7];
    const float* nW1 = (const float*)d_in[8];
    const float* nb1 = (const float*)d_in[9];
    const float* nW2 = (const float*)d_in[10];
    const float* nb2 = (const float*)d_in[11];
    const float* pW1 = (const float*)d_in[12];
    const float* pb1 = (const float*)d_in[13];
    const float* pW2 = (const float*)d_in[14];
    float* out = (float*)d_out;

    float* agg    = (float*)d_ws;                       // [N,128] f32
    float* posacc = agg + (size_t)NNODES * 128;         // [N,3]
    u16* P    = (u16*)(posacc + (size_t)NNODES * 3);    // [N,384] bf16
    u16* eW1T = P + (size_t)NNODES * 384;               // [128][256]
    u16* eW2T = eW1T + 128 * 256;                       // [128][128]
    u16* pW1T = eW2T + 128 * 128;
    u16* nW1T = pW1T + 128 * 128;                       // [128][256]
    u16* nW2T = nW1T + 128 * 256;
    int* counts = (int*)(nW2T + 128 * 128);             // [50048]
    int* delta  = counts + 50048;                       // [50048] (zeroed w/ counts)
    int* excl   = delta + 50048;                        // [50048]
    int* blkSum = excl + 50048;                         // [256]
    int* blkOff = blkSum + 256;                         // [256]
    int* perm   = blkOff + 256;                         // [E]

    hipMemsetAsync(agg, 0, (size_t)NNODES * 131 * sizeof(float), stream);
    hipMemsetAsync(counts, 0, 2 * 50048 * sizeof(int), stream);

    prep_kernel<<<TRN_BLOCKS + (NEDGES + 255) / 256, 256, 0, stream>>>(
        eW1, eW2, pW1, nW1, nW2, eW1T, eW2T, pW1T, nW1T, nW2T, rcv, counts);

    gemm_p<<<(NNODES + 63) / 64, 256, 0, stream>>>(h, eW1T, nW1T, eb1, P);

    scan1<<<SCAN_BLOCKS, 256, 0, stream>>>(counts, excl, blkSum);
    scan2<<<1, 256, 0, stream>>>(blkSum, blkOff);
    scatter_kernel<<<(NEDGES + 255) / 256, 256, 0, stream>>>(
        rcv, excl, blkOff, delta, perm);

    edge_kernel<<<EB, 256, 0, stream>>>(
        P, pos, snd, rcv, perm,
        eW1 + 256 * 128,
        eW2T, eb2, pW1T, pb1, pW2,
        agg, posacc);

    node_kernel<<<(NNODES + 63) / 64, 256, 0, stream>>>(
        P, h, agg, nW1T, nb1, nW2T, nb2, pos, posacc, out);
}

// Round 7
// 460.142 us; speedup vs baseline: 1.9928x; 1.9928x over previous
//
#include <hip/hip_runtime.h>
#include <hip/hip_bf16.h>

#define NNODES 50000
#define NEDGES 800000
#define EB 1024          // edge grid: 4 blocks/CU resident, 128 blocks/XCD
#define SCAN_BLOCKS 196  // ceil(50000/256)
#define TRN_BLOCKS 448   // 114688 weight elems / 256

typedef short bf16x8 __attribute__((ext_vector_type(8)));
typedef float f32x4 __attribute__((ext_vector_type(4)));
typedef unsigned short u16;
typedef unsigned int u32;

__device__ __forceinline__ u16 f2bf(float f) {
    __hip_bfloat16 b = __float2bfloat16(f);
    return *reinterpret_cast<u16*>(&b);
}
__device__ __forceinline__ float bf2f(u16 v) {
    u32 u = ((u32)v) << 16;
    return __uint_as_float(u);
}
__device__ __forceinline__ u32 pack2(float a, float b) {
    __hip_bfloat162 t = __float22bfloat162_rn(float2{a, b});
    return *reinterpret_cast<u32*>(&t);
}
// silu without IEEE divide: x * rcp(1 + 2^(-x*log2e))
__device__ __forceinline__ float fast_silu(float x) {
    float e = __builtin_amdgcn_exp2f(-1.442695040888963f * x);
    return x * __builtin_amdgcn_rcpf(1.0f + e);
}
__device__ __forceinline__ bf16x8 ld8(const u16* p) {
    return *(const bf16x8*)p;
}
__device__ __forceinline__ f32x4 mfma16(bf16x8 a, bf16x8 b, f32x4 c) {
    return __builtin_amdgcn_mfma_f32_16x16x32_bf16(a, b, c, 0, 0, 0);
}
// Barrier that drains LDS ops only — does NOT wait for vector-memory ops,
// so global loads issued before it stay in flight across the barrier.
// Safe: global writes here are atomics nobody re-reads in-kernel; global
// loads get compiler-inserted vmcnt waits at their use sites.
__device__ __forceinline__ void bar_lds() {
    asm volatile("s_waitcnt lgkmcnt(0)\n\ts_barrier" ::: "memory");
}

// ---- prep: 5 weight transposes (fp32->bf16) + receiver histogram ----
__global__ void prep_kernel(const float* __restrict__ eW1, const float* __restrict__ eW2,
                            const float* __restrict__ pW1, const float* __restrict__ nW1,
                            const float* __restrict__ nW2,
                            u16* __restrict__ eW1T, u16* __restrict__ eW2T,
                            u16* __restrict__ pW1T, u16* __restrict__ nW1T,
                            u16* __restrict__ nW2T,
                            const int* __restrict__ rcv, int* __restrict__ counts) {
    int b = blockIdx.x;
    if (b < TRN_BLOCKS) {
        int i = b * 256 + threadIdx.x;
        const float* src; u16* dst; int K;
        if (i < 32768)      { src = eW1; dst = eW1T; K = 256; }
        else if (i < 49152) { src = eW2; dst = eW2T; K = 128; i -= 32768; }
        else if (i < 65536) { src = pW1; dst = pW1T; K = 128; i -= 49152; }
        else if (i < 98304) { src = nW1; dst = nW1T; K = 256; i -= 65536; }
        else                { src = nW2; dst = nW2T; K = 128; i -= 98304; }
        int n = i / K, k = i - n * K;
        dst[i] = f2bf(src[k * 128 + n]);
    } else {
        int e = (b - TRN_BLOCKS) * 256 + threadIdx.x;
        if (e < NEDGES) atomicAdd(&counts[rcv[e]], 1);
    }
}

// ---- P precompute: P[n] = [h@eW1a + eb1/2 | h@eW1b + eb1/2 | h@nW1a] (bf16) ----
__global__ __launch_bounds__(256) void gemm_p(
    const float* __restrict__ h, const u16* __restrict__ eW1T,
    const u16* __restrict__ nW1T, const float* __restrict__ eb1,
    u16* __restrict__ P)
{
    const int tid  = threadIdx.x;
    const int w    = tid >> 6;
    const int lane = tid & 63;
    const int m    = lane & 15;
    const int quad = lane >> 4;
    const int ksub = quad * 8;

    bf16x8 bw[4][6];
    float bias[6];
    #pragma unroll
    for (int cc = 0; cc < 6; cc++) {
        int C = 96 * w + 16 * cc + m;
        const u16* bp;
        if (C < 128)      { bp = eW1T + C * 256;               bias[cc] = 0.5f * eb1[C]; }
        else if (C < 256) { bp = eW1T + (C - 128) * 256 + 128; bias[cc] = 0.5f * eb1[C - 128]; }
        else              { bp = nW1T + (C - 256) * 256;       bias[cc] = 0.f; }
        #pragma unroll
        for (int t = 0; t < 4; t++) bw[t][cc] = ld8(bp + t * 32 + ksub);
    }
    const int base = blockIdx.x * 64;
    #pragma unroll
    for (int mt = 0; mt < 4; mt++) {
        int nm = base + mt * 16 + m;
        if (nm >= NNODES) nm = NNODES - 1;
        bf16x8 afr[4];
        #pragma unroll
        for (int t = 0; t < 4; t++) {
            const float* ap = h + (size_t)nm * 128 + t * 32 + ksub;
            f32x4 lo = *(const f32x4*)ap;
            f32x4 hi = *(const f32x4*)(ap + 4);
            #pragma unroll
            for (int j = 0; j < 4; j++) {
                afr[t][j]     = (short)f2bf(lo[j]);
                afr[t][4 + j] = (short)f2bf(hi[j]);
            }
        }
        f32x4 acc[6];
        #pragma unroll
        for (int cc = 0; cc < 6; cc++) acc[cc] = (f32x4){0,0,0,0};
        #pragma unroll
        for (int t = 0; t < 4; t++)
            #pragma unroll
            for (int cc = 0; cc < 6; cc++)
                acc[cc] = mfma16(afr[t], bw[t][cc], acc[cc]);
        #pragma unroll
        for (int cc = 0; cc < 6; cc++) {
            int C = 96 * w + 16 * cc + m;
            #pragma unroll
            for (int r = 0; r < 4; r++) {
                int nr = base + mt * 16 + quad * 4 + r;
                if (nr < NNODES) P[(size_t)nr * 384 + C] = f2bf(acc[cc][r] + bias[cc]);
            }
        }
    }
}

// ---- scan chain ----
__global__ void scan1(const int* __restrict__ counts, int* __restrict__ excl,
                      int* __restrict__ blkSum) {
    __shared__ int tmp[256];
    int tx = threadIdx.x;
    int i = blockIdx.x * 256 + tx;
    int v = (i < NNODES) ? counts[i] : 0;
    tmp[tx] = v;
    __syncthreads();
    for (int off = 1; off < 256; off <<= 1) {
        int t = (tx >= off) ? tmp[tx - off] : 0;
        __syncthreads();
        tmp[tx] += t;
        __syncthreads();
    }
    if (i < NNODES) excl[i] = tmp[tx] - v;
    if (tx == 255) blkSum[blockIdx.x] = tmp[255];
}
__global__ void scan2(const int* __restrict__ blkSum, int* __restrict__ blkOff) {
    __shared__ int tmp[256];
    int tx = threadIdx.x;
    int v = (tx < SCAN_BLOCKS) ? blkSum[tx] : 0;
    tmp[tx] = v;
    __syncthreads();
    for (int off = 1; off < 256; off <<= 1) {
        int t = (tx >= off) ? tmp[tx - off] : 0;
        __syncthreads();
        tmp[tx] += t;
        __syncthreads();
    }
    if (tx < SCAN_BLOCKS) blkOff[tx] = tmp[tx] - v;
}
// scatter with inlined scan3: p = excl[r] + blkOff[r>>8] + delta[r]++
__global__ void scatter_kernel(const int* __restrict__ rcv, const int* __restrict__ excl,
                               const int* __restrict__ blkOff, int* __restrict__ delta,
                               int* __restrict__ perm) {
    int e = blockIdx.x * 256 + threadIdx.x;
    if (e < NEDGES) {
        int r = rcv[e];
        int p = excl[r] + blkOff[r >> 8] + atomicAdd(&delta[r], 1);
        perm[p] = e;
    }
}

struct __align__(16) EdgeLds {
    u16   m1[64 * 136];       // XOR-swizzled 8-col chunks
    u16   msg[64 * 136];
    float diff[64][4];
    float pcpart[4][64];
    float wlast[128];
    float eb2s[128];          // biases in LDS: after operand swap they are
    float pb1s[128];          // per-(quad,rr) not per-m -> read as b128/tile
    float pw2s[128];          // (keeps persistent VGPRs at the 128 cap)
    int   sndloc[64];
    int   rcvloc[64];
    unsigned long long bmap;  // bit i = (rcv[i] != rcv[i-1]) within tile
};   // ~38.5 KB -> still 4 blocks/CU (<=40KB each)

__global__ __launch_bounds__(256, 4) void edge_kernel(
    const u16* __restrict__ P, const float* __restrict__ pos,
    const int* __restrict__ snd, const int* __restrict__ rcv,
    const int* __restrict__ perm,
    const float* __restrict__ eW1last,
    const u16* __restrict__ eW2T, const float* __restrict__ eb2,
    const u16* __restrict__ pW1T, const float* __restrict__ pb1,
    const float* __restrict__ pW2,
    float* __restrict__ agg, float* __restrict__ posacc)
{
    __shared__ EdgeLds S;
    const int tid  = threadIdx.x;
    const int w    = tid >> 6;
    const int lane = tid & 63;
    const int m    = lane & 15;
    const int quad = lane >> 4;
    const int ksub = quad * 8;

    bf16x8 bw2[4][2], bp1[4][2];
    #pragma unroll
    for (int cc = 0; cc < 2; cc++) {
        int col = (2 * w + cc) * 16 + m;
        #pragma unroll
        for (int t = 0; t < 4; t++) {
            bw2[t][cc] = ld8(eW2T + col * 128 + t * 32 + ksub);
            bp1[t][cc] = ld8(pW1T + col * 128 + t * 32 + ksub);
        }
    }
    if (tid < 128) {
        S.wlast[tid] = eW1last[tid];
        S.eb2s[tid]  = eb2[tid];
        S.pb1s[tid]  = pb1[tid];
        S.pw2s[tid]  = pW2[tid];
    }

    // XCD-chunked tile mapping (kept: neutral-to-positive, L2 locality)
    const int NT  = NEDGES / 64;                 // 12500 (exact)
    const int xcd = blockIdx.x & 7;
    const int ib  = blockIdx.x >> 3;             // 0..127 within XCD
    const int per = (NT + 7) / 8;                // 1563
    const int t0  = xcd * per;
    const int t1  = (t0 + per < NT) ? t0 + per : NT;

    // 1-tile-deep prefetch of edge ids only (3 VGPRs; larger prefetch spills)
    int eg_n = 0, s_n = 0, r_n = 0;
    if (t0 + ib < t1) {
        eg_n = perm[(t0 + ib) * 64 + lane];
        s_n = snd[eg_n]; r_n = rcv[eg_n];
    }

    for (int t = t0 + ib; t < t1; t += 128) {
        const int s = s_n, r = r_n;
        const int tn = t + 128;
        const int tp = (tn < t1) ? tn : t;       // last iter: dummy (discarded)
        int eg2 = perm[tp * 64 + lane];          // prefetch next tile's edge ids

        // pos gather + radial in registers (4x redundant, L1/L2-cached)
        float d0 = pos[s * 3 + 0] - pos[r * 3 + 0];
        float d1 = pos[s * 3 + 1] - pos[r * 3 + 1];
        float d2 = pos[s * 3 + 2] - pos[r * 3 + 2];
        float rad = d0 * d0 + d1 * d1 + d2 * d2;

        bar_lds();   // X1: previous tile's consumers of S.* are done
        if (tid < 64) {
            S.sndloc[tid] = s; S.rcvloc[tid] = r;
            S.diff[tid][0] = d0; S.diff[tid][1] = d1;
            S.diff[tid][2] = d2; S.diff[tid][3] = 0.f;
            int pv = __shfl_up(r, 1);
            unsigned long long bm = __ballot(lane > 0 && r != pv);
            if (tid == 0) S.bmap = bm;
        }
        // ---- layer1: m1 = silu(Pa[s] + Pb[r] + rad*wlast)  (bias pre-folded) ----
        {
            const int sw = lane >> 3;
            const u16* pap = P + (size_t)s * 384 + w * 32;
            const u16* pbp = P + (size_t)r * 384 + 128 + w * 32;
            #pragma unroll
            for (int k = 0; k < 4; k++) {
                bf16x8 va = ld8(pap + k * 8);
                bf16x8 vb = ld8(pbp + k * 8);
                u32 pk[4];
                #pragma unroll
                for (int jj = 0; jj < 4; jj++) {
                    int col = w * 32 + k * 8 + jj * 2;
                    float2 wl = *(const float2*)&S.wlast[col];
                    float v0 = bf2f((u16)va[jj * 2])     + bf2f((u16)vb[jj * 2])     + rad * wl.x;
                    float v1 = bf2f((u16)va[jj * 2 + 1]) + bf2f((u16)vb[jj * 2 + 1]) + rad * wl.y;
                    pk[jj] = pack2(fast_silu(v0), fast_silu(v1));
                }
                int chunk = (w * 4 + k) ^ sw;
                *(uint4*)&S.m1[lane * 136 + chunk * 8] =
                    make_uint4(pk[0], pk[1], pk[2], pk[3]);
            }
        }
        // next tile's snd/rcv (eg2 landed by now)
        s_n = snd[eg2]; r_n = rcv[eg2]; eg_n = eg2;

        bar_lds();   // X2: m1 ready
        // ---- layer2: msg = silu(m1 @ eW2 + b2) ----
        // OPERAND-SWAPPED MFMA: D = W_frag * m1_frag puts lane = edge (m),
        // regs = 4 adjacent hidden cols -> cvt_pk pairs + ds_write_b64.
        {
            f32x4 b2a = *(const f32x4*)&S.eb2s[(2 * w + 0) * 16 + quad * 4];
            f32x4 b2b = *(const f32x4*)&S.eb2s[(2 * w + 1) * 16 + quad * 4];
            #pragma unroll
            for (int mt = 0; mt < 4; mt++) {
                const int rs = mt * 2 + (m >> 3);
                const int row = mt * 16 + m;
                f32x4 acc0 = (f32x4){0,0,0,0}, acc1 = (f32x4){0,0,0,0};
                #pragma unroll
                for (int t4 = 0; t4 < 4; t4++) {
                    bf16x8 a = *(const bf16x8*)&S.m1[row * 136 + ((t4 * 4 + quad) ^ rs) * 8];
                    acc0 = mfma16(bw2[t4][0], a, acc0);
                    acc1 = mfma16(bw2[t4][1], a, acc1);
                }
                u32 q0 = pack2(fast_silu(acc0[0] + b2a[0]), fast_silu(acc0[1] + b2a[1]));
                u32 q1 = pack2(fast_silu(acc0[2] + b2a[2]), fast_silu(acc0[3] + b2a[3]));
                u32 q2 = pack2(fast_silu(acc1[0] + b2b[0]), fast_silu(acc1[1] + b2b[1]));
                u32 q3 = pack2(fast_silu(acc1[2] + b2b[2]), fast_silu(acc1[3] + b2b[3]));
                *(uint2*)&S.msg[row * 136 + (2 * w + 0) * 16 + quad * 4] = make_uint2(q0, q1);
                *(uint2*)&S.msg[row * 136 + (2 * w + 1) * 16 + quad * 4] = make_uint2(q2, q3);
            }
        }
        bar_lds();   // X3: msg ready
        // ---- pos head: pc = silu(msg @ pW1 + pb1) @ pW2 (per-wave partials).
        // Operand-swapped: lane = edge, regs = 4 cols; per-lane partial over
        // its 8 cols, then 2 shfl_xor (16,32) reduce over quad -> pcpart.
        {
            f32x4 p1a = *(const f32x4*)&S.pb1s[(2 * w + 0) * 16 + quad * 4];
            f32x4 p1b = *(const f32x4*)&S.pb1s[(2 * w + 1) * 16 + quad * 4];
            f32x4 w2a = *(const f32x4*)&S.pw2s[(2 * w + 0) * 16 + quad * 4];
            f32x4 w2b = *(const f32x4*)&S.pw2s[(2 * w + 1) * 16 + quad * 4];
            #pragma unroll
            for (int mt = 0; mt < 4; mt++) {
                const int row = mt * 16 + m;
                f32x4 acc0 = (f32x4){0,0,0,0}, acc1 = (f32x4){0,0,0,0};
                #pragma unroll
                for (int t4 = 0; t4 < 4; t4++) {
                    bf16x8 a = *(const bf16x8*)&S.msg[row * 136 + t4 * 32 + ksub];
                    acc0 = mfma16(bp1[t4][0], a, acc0);
                    acc1 = mfma16(bp1[t4][1], a, acc1);
                }
                float part = 0.f;
                #pragma unroll
                for (int rr = 0; rr < 4; rr++)
                    part += fast_silu(acc0[rr] + p1a[rr]) * w2a[rr]
                          + fast_silu(acc1[rr] + p1b[rr]) * w2b[rr];
                part += __shfl_xor(part, 16);
                part += __shfl_xor(part, 32);
                if (quad == 0) S.pcpart[w][mt * 16 + m] = part;
            }
        }
        // ---- agg: uniform segment loop over receiver-sorted rows ----
        {
            int half = tid >> 7, col = tid & 127;
            int r0 = half * 32;
            u32 bm32 = __builtin_amdgcn_readfirstlane((u32)(S.bmap >> r0)) & ~1u;
            float a = 0.f;
            int cur = S.rcvloc[r0];
            int rr = r0;
            const int end0 = r0 + 32;
            while (true) {
                int nb = bm32 ? (r0 + __builtin_ctz(bm32)) : end0;
                for (; rr < nb; ++rr) a += bf2f(S.msg[rr * 136 + col]);
                atomicAdd(&agg[(size_t)cur * 128 + col], a);
                if (nb == end0) break;
                a = 0.f;
                cur = S.rcvloc[nb];
                bm32 &= bm32 - 1;
            }
        }
        bar_lds();   // X4: pcpart ready, msg fully consumed
        if (tid < 192) {
            int ee = tid / 3, c = tid - ee * 3;
            float pc = S.pcpart[0][ee] + S.pcpart[1][ee] + S.pcpart[2][ee] + S.pcpart[3][ee];
            float tr = S.diff[ee][c] * pc;
            tr = fminf(fmaxf(tr, -100.f), 100.f);
            atomicAdd(&posacc[S.sndloc[ee] * 3 + c], tr);
        }
    }
}

// Node MLP (+ fused pos output): h_new = h + (silu([h,agg]@nW1+nb1)@nW2+nb2)
__global__ __launch_bounds__(256, 4) void node_kernel(
    const u16* __restrict__ P, const float* __restrict__ h,
    const float* __restrict__ agg,
    const u16* __restrict__ nW1T, const float* __restrict__ nb1,
    const u16* __restrict__ nW2T, const float* __restrict__ nb2,
    const float* __restrict__ pos, const float* __restrict__ posacc,
    float* __restrict__ out)
{
    __shared__ alignas(16) u16 m1[64 * 136];
    const int tid  = threadIdx.x;
    const int w    = tid >> 6;
    const int lane = tid & 63;
    const int m    = lane & 15;
    const int quad = lane >> 4;
    const int ksub = quad * 8;

    bf16x8 bw1[4][2], bw2[4][2];
    float b1v[2], b2v[2];
    #pragma unroll
    for (int cc = 0; cc < 2; cc++) {
        int col = (2 * w + cc) * 16 + m;
        #pragma unroll
        for (int t = 0; t < 4; t++) {
            bw1[t][cc] = ld8(nW1T + col * 256 + 128 + t * 32 + ksub);  // agg rows of nW1
            bw2[t][cc] = ld8(nW2T + col * 128 + t * 32 + ksub);
        }
        b1v[cc] = nb1[col];
        b2v[cc] = nb2[col];
    }
    const int base = blockIdx.x * 64;
    #pragma unroll
    for (int mt = 0; mt < 4; mt++) {
        int nm = base + mt * 16 + m;
        if (nm >= NNODES) nm = NNODES - 1;
        f32x4 acc0 = (f32x4){0,0,0,0}, acc1 = (f32x4){0,0,0,0};
        #pragma unroll
        for (int t = 0; t < 4; t++) {
            const float* ap = agg + (size_t)nm * 128 + t * 32 + ksub;
            f32x4 lo = *(const f32x4*)ap;
            f32x4 hi = *(const f32x4*)(ap + 4);
            bf16x8 a;
            #pragma unroll
            for (int j = 0; j < 4; j++) {
                a[j]     = (short)f2bf(lo[j]);
                a[4 + j] = (short)f2bf(hi[j]);
            }
            acc0 = mfma16(a, bw1[t][0], acc0);
            acc1 = mfma16(a, bw1[t][1], acc1);
        }
        #pragma unroll
        for (int cc = 0; cc < 2; cc++) {
            f32x4 acc = cc ? acc1 : acc0;
            int col = (2 * w + cc) * 16 + m;
            #pragma unroll
            for (int rr = 0; rr < 4; rr++) {
                int row = mt * 16 + quad * 4 + rr;
                int nrc = base + row; if (nrc >= NNODES) nrc = NNODES - 1;
                float v = acc[rr] + bf2f(P[(size_t)nrc * 384 + 256 + col]) + b1v[cc];
                m1[row * 136 + col] = f2bf(fast_silu(v));
            }
        }
    }
    __syncthreads();
    #pragma unroll
    for (int mt = 0; mt < 4; mt++) {
        f32x4 acc0 = (f32x4){0,0,0,0}, acc1 = (f32x4){0,0,0,0};
        #pragma unroll
        for (int t = 0; t < 4; t++) {
            bf16x8 a = *(const bf16x8*)&m1[(mt * 16 + m) * 136 + t * 32 + ksub];
            acc0 = mfma16(a, bw2[t][0], acc0);
            acc1 = mfma16(a, bw2[t][1], acc1);
        }
        #pragma unroll
        for (int cc = 0; cc < 2; cc++) {
            f32x4 acc = cc ? acc1 : acc0;
            int col = (2 * w + cc) * 16 + m;
            #pragma unroll
            for (int rr = 0; rr < 4; rr++) {
                int nr = base + mt * 16 + quad * 4 + rr;
                if (nr < NNODES)
                    out[(size_t)nr * 128 + col] = acc[rr] + b2v[cc] + h[(size_t)nr * 128 + col];
            }
        }
    }
    // fused pos output: 192 elems per block covers 150144 >= 150000
    if (tid < 192) {
        int i = blockIdx.x * 192 + tid;
        if (i < NNODES * 3) out[NNODES * 128 + i] = pos[i] + posacc[i];
    }
}

extern "C" void kernel_launch(void* const* d_in, const int* in_sizes, int n_in,
                              void* d_out, int out_size, void* d_ws, size_t ws_size,
                              hipStream_t stream) {
    (void)in_sizes; (void)n_in; (void)out_size; (void)ws_size;
    const float* h   = (const float*)d_in[0];
    const float* pos = (const float*)d_in[1];
    const int*   snd = (const int*)d_in[2];
    const int*   rcv = (const int*)d_in[3];
    const float* eW1 = (const float*)d_in[4];
    const float* eb1 = (const float*)d_in[5];
    const float* eW2 = (const float*)d_in[6];
    const float* eb2 = (const float*)d_in[7];
    const float* nW1 = (const float*)d_in[8];
    const float* nb1 = (const float*)d_in[9];
    const float* nW2 = (const float*)d_in[10];
    const float* nb2 = (const float*)d_in[11];
    const float* pW1 = (const float*)d_in[12];
    const float* pb1 = (const float*)d_in[13];
    const float* pW2 = (const float*)d_in[14];
    float* out = (float*)d_out;

    float* agg    = (float*)d_ws;                       // [N,128] f32
    float* posacc = agg + (size_t)NNODES * 128;         // [N,3]
    u16* P    = (u16*)(posacc + (size_t)NNODES * 3);    // [N,384] bf16
    u16* eW1T = P + (size_t)NNODES * 384;               // [128][256]
    u16* eW2T = eW1T + 128 * 256;                       // [128][128]
    u16* pW1T = eW2T + 128 * 128;
    u16* nW1T = pW1T + 128 * 128;                       // [128][256]
    u16* nW2T = nW1T + 128 * 256;
    int* counts = (int*)(nW2T + 128 * 128);             // [50048]
    int* delta  = counts + 50048;                       // [50048] (zeroed w/ counts)
    int* excl   = delta + 50048;                        // [50048]
    int* blkSum = excl + 50048;                         // [256]
    int* blkOff = blkSum + 256;                         // [256]
    int* perm   = blkOff + 256;                         // [E]

    hipMemsetAsync(agg, 0, (size_t)NNODES * 131 * sizeof(float), stream);
    hipMemsetAsync(counts, 0, 2 * 50048 * sizeof(int), stream);

    prep_kernel<<<TRN_BLOCKS + (NEDGES + 255) / 256, 256, 0, stream>>>(
        eW1, eW2, pW1, nW1, nW2, eW1T, eW2T, pW1T, nW1T, nW2T, rcv, counts);

    gemm_p<<<(NNODES + 63) / 64, 256, 0, stream>>>(h, eW1T, nW1T, eb1, P);

    scan1<<<SCAN_BLOCKS, 256, 0, stream>>>(counts, excl, blkSum);
    scan2<<<1, 256, 0, stream>>>(blkSum, blkOff);
    scatter_kernel<<<(NEDGES + 255) / 256, 256, 0, stream>>>(
        rcv, excl, blkOff, delta, perm);

    edge_kernel<<<EB, 256, 0, stream>>>(
        P, pos, snd, rcv, perm,
        eW1 + 256 * 128,
        eW2T, eb2, pW1T, pb1, pW2,
        agg, posacc);

    node_kernel<<<(NNODES + 63) / 64, 256, 0, stream>>>(
        P, h, agg, nW1T, nb1, nW2T, nb2, pos, posacc, out);
}

// Round 8
// 454.245 us; speedup vs baseline: 2.0187x; 1.0130x over previous
//
#include <hip/hip_runtime.h>
#include <hip/hip_bf16.h>

#define NNODES 50000
#define NEDGES 800000
#define EB 1024          // edge grid: 4 blocks/CU resident, 128 blocks/XCD
#define SCAN_BLOCKS 196  // ceil(50000/256)
#define TRN_BLOCKS 448   // 114688 weight elems / 256

typedef short bf16x8 __attribute__((ext_vector_type(8)));
typedef float f32x4 __attribute__((ext_vector_type(4)));
typedef unsigned short u16;
typedef unsigned int u32;

__device__ __forceinline__ u16 f2bf(float f) {
    __hip_bfloat16 b = __float2bfloat16(f);
    return *reinterpret_cast<u16*>(&b);
}
__device__ __forceinline__ float bf2f(u16 v) {
    u32 u = ((u32)v) << 16;
    return __uint_as_float(u);
}
__device__ __forceinline__ u32 pack2(float a, float b) {
    __hip_bfloat162 t = __float22bfloat162_rn(float2{a, b});
    return *reinterpret_cast<u32*>(&t);
}
// silu without IEEE divide: x * rcp(1 + 2^(-x*log2e))
__device__ __forceinline__ float fast_silu(float x) {
    float e = __builtin_amdgcn_exp2f(-1.442695040888963f * x);
    return x * __builtin_amdgcn_rcpf(1.0f + e);
}
__device__ __forceinline__ bf16x8 ld8(const u16* p) {
    return *(const bf16x8*)p;
}
__device__ __forceinline__ f32x4 mfma16(bf16x8 a, bf16x8 b, f32x4 c) {
    return __builtin_amdgcn_mfma_f32_16x16x32_bf16(a, b, c, 0, 0, 0);
}
// Barrier that drains LDS ops only — does NOT wait for vector-memory ops,
// so global loads issued before it stay in flight across the barrier.
// Safe: global writes here are atomics nobody re-reads in-kernel; global
// loads get compiler-inserted vmcnt waits at their use sites.
__device__ __forceinline__ void bar_lds() {
    asm volatile("s_waitcnt lgkmcnt(0)\n\ts_barrier" ::: "memory");
}

// ---- prep: 5 weight transposes (fp32->bf16) + receiver histogram ----
__global__ void prep_kernel(const float* __restrict__ eW1, const float* __restrict__ eW2,
                            const float* __restrict__ pW1, const float* __restrict__ nW1,
                            const float* __restrict__ nW2,
                            u16* __restrict__ eW1T, u16* __restrict__ eW2T,
                            u16* __restrict__ pW1T, u16* __restrict__ nW1T,
                            u16* __restrict__ nW2T,
                            const int* __restrict__ rcv, int* __restrict__ counts) {
    int b = blockIdx.x;
    if (b < TRN_BLOCKS) {
        int i = b * 256 + threadIdx.x;
        const float* src; u16* dst; int K;
        if (i < 32768)      { src = eW1; dst = eW1T; K = 256; }
        else if (i < 49152) { src = eW2; dst = eW2T; K = 128; i -= 32768; }
        else if (i < 65536) { src = pW1; dst = pW1T; K = 128; i -= 49152; }
        else if (i < 98304) { src = nW1; dst = nW1T; K = 256; i -= 65536; }
        else                { src = nW2; dst = nW2T; K = 128; i -= 98304; }
        int n = i / K, k = i - n * K;
        dst[i] = f2bf(src[k * 128 + n]);
    } else {
        int e = (b - TRN_BLOCKS) * 256 + threadIdx.x;
        if (e < NEDGES) atomicAdd(&counts[rcv[e]], 1);
    }
}

// ---- P precompute: P[n] = [h@eW1a + eb1/2 | h@eW1b + eb1/2 | h@nW1a] (bf16) ----
__global__ __launch_bounds__(256) void gemm_p(
    const float* __restrict__ h, const u16* __restrict__ eW1T,
    const u16* __restrict__ nW1T, const float* __restrict__ eb1,
    u16* __restrict__ P)
{
    const int tid  = threadIdx.x;
    const int w    = tid >> 6;
    const int lane = tid & 63;
    const int m    = lane & 15;
    const int quad = lane >> 4;
    const int ksub = quad * 8;

    bf16x8 bw[4][6];
    float bias[6];
    #pragma unroll
    for (int cc = 0; cc < 6; cc++) {
        int C = 96 * w + 16 * cc + m;
        const u16* bp;
        if (C < 128)      { bp = eW1T + C * 256;               bias[cc] = 0.5f * eb1[C]; }
        else if (C < 256) { bp = eW1T + (C - 128) * 256 + 128; bias[cc] = 0.5f * eb1[C - 128]; }
        else              { bp = nW1T + (C - 256) * 256;       bias[cc] = 0.f; }
        #pragma unroll
        for (int t = 0; t < 4; t++) bw[t][cc] = ld8(bp + t * 32 + ksub);
    }
    const int base = blockIdx.x * 64;
    #pragma unroll
    for (int mt = 0; mt < 4; mt++) {
        int nm = base + mt * 16 + m;
        if (nm >= NNODES) nm = NNODES - 1;
        bf16x8 afr[4];
        #pragma unroll
        for (int t = 0; t < 4; t++) {
            const float* ap = h + (size_t)nm * 128 + t * 32 + ksub;
            f32x4 lo = *(const f32x4*)ap;
            f32x4 hi = *(const f32x4*)(ap + 4);
            #pragma unroll
            for (int j = 0; j < 4; j++) {
                afr[t][j]     = (short)f2bf(lo[j]);
                afr[t][4 + j] = (short)f2bf(hi[j]);
            }
        }
        f32x4 acc[6];
        #pragma unroll
        for (int cc = 0; cc < 6; cc++) acc[cc] = (f32x4){0,0,0,0};
        #pragma unroll
        for (int t = 0; t < 4; t++)
            #pragma unroll
            for (int cc = 0; cc < 6; cc++)
                acc[cc] = mfma16(afr[t], bw[t][cc], acc[cc]);
        #pragma unroll
        for (int cc = 0; cc < 6; cc++) {
            int C = 96 * w + 16 * cc + m;
            #pragma unroll
            for (int r = 0; r < 4; r++) {
                int nr = base + mt * 16 + quad * 4 + r;
                if (nr < NNODES) P[(size_t)nr * 384 + C] = f2bf(acc[cc][r] + bias[cc]);
            }
        }
    }
}

// ---- scan chain ----
__global__ void scan1(const int* __restrict__ counts, int* __restrict__ excl,
                      int* __restrict__ blkSum) {
    __shared__ int tmp[256];
    int tx = threadIdx.x;
    int i = blockIdx.x * 256 + tx;
    int v = (i < NNODES) ? counts[i] : 0;
    tmp[tx] = v;
    __syncthreads();
    for (int off = 1; off < 256; off <<= 1) {
        int t = (tx >= off) ? tmp[tx - off] : 0;
        __syncthreads();
        tmp[tx] += t;
        __syncthreads();
    }
    if (i < NNODES) excl[i] = tmp[tx] - v;
    if (tx == 255) blkSum[blockIdx.x] = tmp[255];
}
__global__ void scan2(const int* __restrict__ blkSum, int* __restrict__ blkOff) {
    __shared__ int tmp[256];
    int tx = threadIdx.x;
    int v = (tx < SCAN_BLOCKS) ? blkSum[tx] : 0;
    tmp[tx] = v;
    __syncthreads();
    for (int off = 1; off < 256; off <<= 1) {
        int t = (tx >= off) ? tmp[tx - off] : 0;
        __syncthreads();
        tmp[tx] += t;
        __syncthreads();
    }
    if (tx < SCAN_BLOCKS) blkOff[tx] = tmp[tx] - v;
}
__global__ void scan3(const int* __restrict__ excl, const int* __restrict__ blkOff,
                      int* __restrict__ cursor) {
    int i = blockIdx.x * 256 + threadIdx.x;
    if (i < NNODES) cursor[i] = excl[i] + blkOff[blockIdx.x];
}
__global__ void scatter_kernel(const int* __restrict__ rcv, int* __restrict__ cursor,
                               int* __restrict__ perm) {
    int e = blockIdx.x * 256 + threadIdx.x;
    if (e < NEDGES) {
        int p = atomicAdd(&cursor[rcv[e]], 1);
        perm[p] = e;
    }
}

struct __align__(16) EdgeLds {
    u16   m1[64 * 136];       // XOR-swizzled 8-col chunks
    u16   msg[64 * 136];
    float diff[64][4];
    float pcpart[4][64];
    float wlast[128];
    int   sndloc[64];
    int   rcvloc[64];
    unsigned long long bmap;  // bit i = (rcv[i] != rcv[i-1]) within tile
};   // ~37 KB -> 4 blocks/CU

__global__ __launch_bounds__(256, 4) void edge_kernel(
    const u16* __restrict__ P, const float* __restrict__ pos,
    const int* __restrict__ snd, const int* __restrict__ rcv,
    const int* __restrict__ perm,
    const float* __restrict__ eW1last,
    const u16* __restrict__ eW2T, const float* __restrict__ eb2,
    const u16* __restrict__ pW1T, const float* __restrict__ pb1,
    const float* __restrict__ pW2,
    float* __restrict__ agg, float* __restrict__ posacc)
{
    __shared__ EdgeLds S;
    const int tid  = threadIdx.x;
    const int w    = tid >> 6;
    const int lane = tid & 63;
    const int m    = lane & 15;
    const int quad = lane >> 4;
    const int ksub = quad * 8;

    bf16x8 bw2[4][2], bp1[4][2];
    float b2v[2], pb1v[2], pw2v[2];
    #pragma unroll
    for (int cc = 0; cc < 2; cc++) {
        int col = (2 * w + cc) * 16 + m;
        #pragma unroll
        for (int t = 0; t < 4; t++) {
            bw2[t][cc] = ld8(eW2T + col * 128 + t * 32 + ksub);
            bp1[t][cc] = ld8(pW1T + col * 128 + t * 32 + ksub);
        }
        b2v[cc]  = eb2[col];
        pb1v[cc] = pb1[col];
        pw2v[cc] = pW2[col];
    }
    if (tid < 128) S.wlast[tid] = eW1last[tid];

    // XCD-chunked tile mapping (measured neutral-to-positive for L2 locality)
    const int NT  = NEDGES / 64;                 // 12500 (exact)
    const int xcd = blockIdx.x & 7;
    const int ib  = blockIdx.x >> 3;             // 0..127 within XCD
    const int per = (NT + 7) / 8;                // 1563
    const int t0  = xcd * per;
    const int t1  = (t0 + per < NT) ? t0 + per : NT;

    // 1-tile-deep prefetch of edge ids only (3 VGPRs; larger prefetch spills)
    int eg_n = 0, s_n = 0, r_n = 0;
    if (t0 + ib < t1) {
        eg_n = perm[(t0 + ib) * 64 + lane];
        s_n = snd[eg_n]; r_n = rcv[eg_n];
    }

    for (int t = t0 + ib; t < t1; t += 128) {
        const int s = s_n, r = r_n;
        const int tn = t + 128;
        const int tp = (tn < t1) ? tn : t;       // last iter: dummy (discarded)
        int eg2 = perm[tp * 64 + lane];          // prefetch next tile's edge ids

        // pos gather + radial in registers (4x redundant, L1/L2-cached)
        float d0 = pos[s * 3 + 0] - pos[r * 3 + 0];
        float d1 = pos[s * 3 + 1] - pos[r * 3 + 1];
        float d2 = pos[s * 3 + 2] - pos[r * 3 + 2];
        float rad = d0 * d0 + d1 * d1 + d2 * d2;

        bar_lds();   // X1: previous tile's consumers of S.* are done
        if (tid < 64) {
            S.sndloc[tid] = s; S.rcvloc[tid] = r;
            S.diff[tid][0] = d0; S.diff[tid][1] = d1;
            S.diff[tid][2] = d2; S.diff[tid][3] = 0.f;
            int pv = __shfl_up(r, 1);
            unsigned long long bm = __ballot(lane > 0 && r != pv);
            if (tid == 0) S.bmap = bm;
        }
        // ---- layer1: m1 = silu(Pa[s] + Pb[r] + rad*wlast)  (bias pre-folded) ----
        {
            const int sw = lane >> 3;
            const u16* pap = P + (size_t)s * 384 + w * 32;
            const u16* pbp = P + (size_t)r * 384 + 128 + w * 32;
            #pragma unroll
            for (int k = 0; k < 4; k++) {
                bf16x8 va = ld8(pap + k * 8);
                bf16x8 vb = ld8(pbp + k * 8);
                u32 pk[4];
                #pragma unroll
                for (int jj = 0; jj < 4; jj++) {
                    int col = w * 32 + k * 8 + jj * 2;
                    float2 wl = *(const float2*)&S.wlast[col];
                    float v0 = bf2f((u16)va[jj * 2])     + bf2f((u16)vb[jj * 2])     + rad * wl.x;
                    float v1 = bf2f((u16)va[jj * 2 + 1]) + bf2f((u16)vb[jj * 2 + 1]) + rad * wl.y;
                    pk[jj] = pack2(fast_silu(v0), fast_silu(v1));
                }
                int chunk = (w * 4 + k) ^ sw;
                *(uint4*)&S.m1[lane * 136 + chunk * 8] =
                    make_uint4(pk[0], pk[1], pk[2], pk[3]);
            }
        }
        // next tile's snd/rcv (eg2 landed by now)
        s_n = snd[eg2]; r_n = rcv[eg2]; eg_n = eg2;

        bar_lds();   // X2: m1 ready
        // ---- layer2: msg = silu(m1 @ eW2 + b2) ----
        #pragma unroll
        for (int mt = 0; mt < 4; mt++) {
            const int rs = mt * 2 + (m >> 3);
            const int row = mt * 16 + m;
            f32x4 acc0 = (f32x4){0,0,0,0}, acc1 = (f32x4){0,0,0,0};
            #pragma unroll
            for (int t4 = 0; t4 < 4; t4++) {
                bf16x8 a = *(const bf16x8*)&S.m1[row * 136 + ((t4 * 4 + quad) ^ rs) * 8];
                acc0 = mfma16(a, bw2[t4][0], acc0);
                acc1 = mfma16(a, bw2[t4][1], acc1);
            }
            #pragma unroll
            for (int cc = 0; cc < 2; cc++) {
                f32x4 acc = cc ? acc1 : acc0;
                int col = (2 * w + cc) * 16 + m;
                #pragma unroll
                for (int rr = 0; rr < 4; rr++) {
                    int orow = mt * 16 + quad * 4 + rr;
                    S.msg[orow * 136 + col] = f2bf(fast_silu(acc[rr] + b2v[cc]));
                }
            }
        }
        bar_lds();   // X3: msg ready
        // ---- pos head: pc = silu(msg @ pW1 + pb1) @ pW2 (per-wave partials) ----
        #pragma unroll
        for (int mt = 0; mt < 4; mt++) {
            f32x4 acc0 = (f32x4){0,0,0,0}, acc1 = (f32x4){0,0,0,0};
            #pragma unroll
            for (int t4 = 0; t4 < 4; t4++) {
                bf16x8 a = *(const bf16x8*)&S.msg[(mt * 16 + m) * 136 + t4 * 32 + ksub];
                acc0 = mfma16(a, bp1[t4][0], acc0);
                acc1 = mfma16(a, bp1[t4][1], acc1);
            }
            float p4[4];
            #pragma unroll
            for (int rr = 0; rr < 4; rr++)
                p4[rr] = fast_silu(acc0[rr] + pb1v[0]) * pw2v[0]
                       + fast_silu(acc1[rr] + pb1v[1]) * pw2v[1];
            #pragma unroll
            for (int mask = 1; mask < 16; mask <<= 1) {
                #pragma unroll
                for (int rr = 0; rr < 4; rr++) p4[rr] += __shfl_xor(p4[rr], mask);
            }
            if (m == 0) {
                #pragma unroll
                for (int rr = 0; rr < 4; rr++)
                    S.pcpart[w][mt * 16 + quad * 4 + rr] = p4[rr];
            }
        }
        // ---- agg: uniform segment loop over receiver-sorted rows ----
        {
            int half = tid >> 7, col = tid & 127;
            int r0 = half * 32;
            u32 bm32 = __builtin_amdgcn_readfirstlane((u32)(S.bmap >> r0)) & ~1u;
            float a = 0.f;
            int cur = S.rcvloc[r0];
            int rr = r0;
            const int end0 = r0 + 32;
            while (true) {
                int nb = bm32 ? (r0 + __builtin_ctz(bm32)) : end0;
                for (; rr < nb; ++rr) a += bf2f(S.msg[rr * 136 + col]);
                atomicAdd(&agg[(size_t)cur * 128 + col], a);
                if (nb == end0) break;
                a = 0.f;
                cur = S.rcvloc[nb];
                bm32 &= bm32 - 1;
            }
        }
        bar_lds();   // X4: pcpart ready, msg fully consumed
        if (tid < 192) {
            int ee = tid / 3, c = tid - ee * 3;
            float pc = S.pcpart[0][ee] + S.pcpart[1][ee] + S.pcpart[2][ee] + S.pcpart[3][ee];
            float tr = S.diff[ee][c] * pc;
            tr = fminf(fmaxf(tr, -100.f), 100.f);
            atomicAdd(&posacc[S.sndloc[ee] * 3 + c], tr);
        }
    }
}

// Node MLP (+ fused pos output): h_new = h + (silu([h,agg]@nW1+nb1)@nW2+nb2)
__global__ __launch_bounds__(256, 4) void node_kernel(
    const u16* __restrict__ P, const float* __restrict__ h,
    const float* __restrict__ agg,
    const u16* __restrict__ nW1T, const float* __restrict__ nb1,
    const u16* __restrict__ nW2T, const float* __restrict__ nb2,
    const float* __restrict__ pos, const float* __restrict__ posacc,
    float* __restrict__ out)
{
    __shared__ alignas(16) u16 m1[64 * 136];
    const int tid  = threadIdx.x;
    const int w    = tid >> 6;
    const int lane = tid & 63;
    const int m    = lane & 15;
    const int quad = lane >> 4;
    const int ksub = quad * 8;

    bf16x8 bw1[4][2], bw2[4][2];
    float b1v[2], b2v[2];
    #pragma unroll
    for (int cc = 0; cc < 2; cc++) {
        int col = (2 * w + cc) * 16 + m;
        #pragma unroll
        for (int t = 0; t < 4; t++) {
            bw1[t][cc] = ld8(nW1T + col * 256 + 128 + t * 32 + ksub);  // agg rows of nW1
            bw2[t][cc] = ld8(nW2T + col * 128 + t * 32 + ksub);
        }
        b1v[cc] = nb1[col];
        b2v[cc] = nb2[col];
    }
    const int base = blockIdx.x * 64;
    #pragma unroll
    for (int mt = 0; mt < 4; mt++) {
        int nm = base + mt * 16 + m;
        if (nm >= NNODES) nm = NNODES - 1;
        f32x4 acc0 = (f32x4){0,0,0,0}, acc1 = (f32x4){0,0,0,0};
        #pragma unroll
        for (int t = 0; t < 4; t++) {
            const float* ap = agg + (size_t)nm * 128 + t * 32 + ksub;
            f32x4 lo = *(const f32x4*)ap;
            f32x4 hi = *(const f32x4*)(ap + 4);
            bf16x8 a;
            #pragma unroll
            for (int j = 0; j < 4; j++) {
                a[j]     = (short)f2bf(lo[j]);
                a[4 + j] = (short)f2bf(hi[j]);
            }
            acc0 = mfma16(a, bw1[t][0], acc0);
            acc1 = mfma16(a, bw1[t][1], acc1);
        }
        #pragma unroll
        for (int cc = 0; cc < 2; cc++) {
            f32x4 acc = cc ? acc1 : acc0;
            int col = (2 * w + cc) * 16 + m;
            #pragma unroll
            for (int rr = 0; rr < 4; rr++) {
                int row = mt * 16 + quad * 4 + rr;
                int nrc = base + row; if (nrc >= NNODES) nrc = NNODES - 1;
                float v = acc[rr] + bf2f(P[(size_t)nrc * 384 + 256 + col]) + b1v[cc];
                m1[row * 136 + col] = f2bf(fast_silu(v));
            }
        }
    }
    __syncthreads();
    #pragma unroll
    for (int mt = 0; mt < 4; mt++) {
        f32x4 acc0 = (f32x4){0,0,0,0}, acc1 = (f32x4){0,0,0,0};
        #pragma unroll
        for (int t = 0; t < 4; t++) {
            bf16x8 a = *(const bf16x8*)&m1[(mt * 16 + m) * 136 + t * 32 + ksub];
            acc0 = mfma16(a, bw2[t][0], acc0);
            acc1 = mfma16(a, bw2[t][1], acc1);
        }
        #pragma unroll
        for (int cc = 0; cc < 2; cc++) {
            f32x4 acc = cc ? acc1 : acc0;
            int col = (2 * w + cc) * 16 + m;
            #pragma unroll
            for (int rr = 0; rr < 4; rr++) {
                int nr = base + mt * 16 + quad * 4 + rr;
                if (nr < NNODES)
                    out[(size_t)nr * 128 + col] = acc[rr] + b2v[cc] + h[(size_t)nr * 128 + col];
            }
        }
    }
    // fused pos output: 192 elems per block covers 150144 >= 150000
    if (tid < 192) {
        int i = blockIdx.x * 192 + tid;
        if (i < NNODES * 3) out[NNODES * 128 + i] = pos[i] + posacc[i];
    }
}

extern "C" void kernel_launch(void* const* d_in, const int* in_sizes, int n_in,
                              void* d_out, int out_size, void* d_ws, size_t ws_size,
                              hipStream_t stream) {
    (void)in_sizes; (void)n_in; (void)out_size; (void)ws_size;
    const float* h   = (const float*)d_in[0];
    const float* pos = (const float*)d_in[1];
    const int*   snd = (const int*)d_in[2];
    const int*   rcv = (const int*)d_in[3];
    const float* eW1 = (const float*)d_in[4];
    const float* eb1 = (const float*)d_in[5];
    const float* eW2 = (const float*)d_in[6];
    const float* eb2 = (const float*)d_in[7];
    const float* nW1 = (const float*)d_in[8];
    const float* nb1 = (const float*)d_in[9];
    const float* nW2 = (const float*)d_in[10];
    const float* nb2 = (const float*)d_in[11];
    const float* pW1 = (const float*)d_in[12];
    const float* pb1 = (const float*)d_in[13];
    const float* pW2 = (const float*)d_in[14];
    float* out = (float*)d_out;

    float* agg    = (float*)d_ws;                       // [N,128] f32
    float* posacc = agg + (size_t)NNODES * 128;         // [N,3]
    u16* P    = (u16*)(posacc + (size_t)NNODES * 3);    // [N,384] bf16
    u16* eW1T = P + (size_t)NNODES * 384;               // [128][256]
    u16* eW2T = eW1T + 128 * 256;                       // [128][128]
    u16* pW1T = eW2T + 128 * 128;
    u16* nW1T = pW1T + 128 * 128;                       // [128][256]
    u16* nW2T = nW1T + 128 * 256;
    int* counts = (int*)(nW2T + 128 * 128);             // [50048]
    int* excl   = counts + 50048;
    int* blkSum = excl + 50048;                         // [256]
    int* blkOff = blkSum + 256;                         // [256]
    int* cursor = blkOff + 256;                         // [50048]
    int* perm   = cursor + 50048;                       // [E]

    hipMemsetAsync(agg, 0, (size_t)NNODES * 131 * sizeof(float), stream);
    hipMemsetAsync(counts, 0, 50048 * sizeof(int), stream);

    prep_kernel<<<TRN_BLOCKS + (NEDGES + 255) / 256, 256, 0, stream>>>(
        eW1, eW2, pW1, nW1, nW2, eW1T, eW2T, pW1T, nW1T, nW2T, rcv, counts);

    gemm_p<<<(NNODES + 63) / 64, 256, 0, stream>>>(h, eW1T, nW1T, eb1, P);

    scan1<<<SCAN_BLOCKS, 256, 0, stream>>>(counts, excl, blkSum);
    scan2<<<1, 256, 0, stream>>>(blkSum, blkOff);
    scan3<<<SCAN_BLOCKS, 256, 0, stream>>>(excl, blkOff, cursor);
    scatter_kernel<<<(NEDGES + 255) / 256, 256, 0, stream>>>(rcv, cursor, perm);

    edge_kernel<<<EB, 256, 0, stream>>>(
        P, pos, snd, rcv, perm,
        eW1 + 256 * 128,
        eW2T, eb2, pW1T, pb1, pW2,
        agg, posacc);

    node_kernel<<<(NNODES + 63) / 64, 256, 0, stream>>>(
        P, h, agg, nW1T, nb1, nW2T, nb2, pos, posacc, out);
}